// Round 3
// baseline (730.648 us; speedup 1.0000x reference)
//
#include <hip/hip_runtime.h>
#include <hip/hip_bf16.h>

// RelationalMemoryCoreCell on MI355X (gfx950).
// B=256, S=16, H=8, HS=128, D=1024, M=1024, R=B*S=4096.
// ALL inputs are fp32 (reference dtype). Output fp32 (2 x [256,16,1024] concat).
//
// Workspace layout (12 MB; fully rewritten every call):
//   float ws[0      .. 262144)  : dense_inputs = inputs@W_emb + b_emb   [256,1024] fp32
//   float ws[262144 .. 524288)  : xf = inputs@W_wf                      [256,1024] fp32
//   float ws[524288 .. 786432)  : xi = inputs@W_wi
//   float ws[786432 ..1048576)  : xo = inputs@W_wo
//   bf16  at byte offset 4MB    : mp = m_state + attended               [4096,1024] bf16 (8 MB)

typedef __hip_bfloat16 bf16;

__device__ __forceinline__ float b2f(bf16 x) { return __bfloat162float(x); }
__device__ __forceinline__ bf16  f2b(float x) { return __float2bfloat16(x); }
__device__ __forceinline__ float sig(float x) { return 1.0f / (1.0f + __expf(-x)); }

#define RMC_B  256
#define RMC_S  16
#define RMC_H  8
#define RMC_HS 128
#define RMC_D  1024
#define RMC_M  1024
#define RMC_R  4096   // B*S

// ---------------------------------------------------------------------------
// Kernel 1: four [256,1024] @ [1024,1024] GEMMs (blockIdx.z selects which).
// which==0: W_emb (+b_emb) -> dense; 1: W_wf -> xf; 2: W_wi -> xi; 3: W_wo -> xo
// 64x64 tile, 16x16 threads, 4x4 per thread, BK=16.
// ---------------------------------------------------------------------------
__global__ __launch_bounds__(256) void k_xgemm(
    const float* __restrict__ inputs,
    const float* __restrict__ W_emb, const float* __restrict__ b_emb,
    const float* __restrict__ W_wf, const float* __restrict__ W_wi,
    const float* __restrict__ W_wo,
    float* __restrict__ ws)
{
    const int which = blockIdx.z;
    const float* W = (which == 0) ? W_emb : (which == 1) ? W_wf : (which == 2) ? W_wi : W_wo;
    float* out = ws + which * (RMC_B * RMC_M);

    const int n0 = blockIdx.x * 64;
    const int m0 = blockIdx.y * 64;
    const int tx = threadIdx.x, ty = threadIdx.y;
    const int tid = ty * 16 + tx;

    __shared__ float As[16][64];   // As[k][m]
    __shared__ float Bs[16][64];   // Bs[k][n]

    float acc[4][4] = {};

    for (int k0 = 0; k0 < RMC_D; k0 += 16) {
        #pragma unroll
        for (int i = 0; i < 4; ++i) {
            int idx = tid + i * 256;          // 0..1023
            int row = idx >> 4, kk = idx & 15;
            As[kk][row] = inputs[(m0 + row) * RMC_D + k0 + kk];
        }
        #pragma unroll
        for (int i = 0; i < 4; ++i) {
            int idx = tid + i * 256;
            int kk = idx >> 6, col = idx & 63;
            Bs[kk][col] = W[(k0 + kk) * RMC_M + n0 + col];
        }
        __syncthreads();
        #pragma unroll
        for (int kk = 0; kk < 16; ++kk) {
            float a[4], b[4];
            #pragma unroll
            for (int i = 0; i < 4; ++i) a[i] = As[kk][ty * 4 + i];
            #pragma unroll
            for (int j = 0; j < 4; ++j) b[j] = Bs[kk][tx * 4 + j];
            #pragma unroll
            for (int i = 0; i < 4; ++i)
                #pragma unroll
                for (int j = 0; j < 4; ++j)
                    acc[i][j] += a[i] * b[j];
        }
        __syncthreads();
    }

    #pragma unroll
    for (int i = 0; i < 4; ++i) {
        int row = m0 + ty * 4 + i;
        #pragma unroll
        for (int j = 0; j < 4; ++j) {
            int col = n0 + tx * 4 + j;
            float v = acc[i][j];
            if (which == 0) v += b_emb[col];
            out[row * RMC_M + col] = v;
        }
    }
}

// ---------------------------------------------------------------------------
// Kernel 2: attention per (b,h). q = m_state head slice [16,128];
// kv = [m_state slice ; dense slice] [17,128]. mp = m_state + attn@kv (bf16).
// ---------------------------------------------------------------------------
__global__ __launch_bounds__(256) void k_attn(
    const float* __restrict__ m_state,  // [4096,1024]
    const float* __restrict__ dense,    // [256,1024]
    bf16* __restrict__ mp)              // [4096,1024]
{
    const int b = blockIdx.x >> 3;
    const int h = blockIdx.x & 7;
    const int tid = threadIdx.x;

    __shared__ float kv[17][RMC_HS];
    __shared__ float sc[16][18];

    for (int idx = tid; idx < 17 * RMC_HS; idx += 256) {
        int r = idx >> 7, d = idx & 127;
        float v;
        if (r < 16) v = m_state[(b * RMC_S + r) * RMC_M + h * RMC_HS + d];
        else        v = dense[b * RMC_M + h * RMC_HS + d];
        kv[r][d] = v;
    }
    __syncthreads();

    // scores = (q . k) / sqrt(128); q rows are kv rows 0..15
    for (int p = tid; p < 16 * 17; p += 256) {
        int qi = p / 17, ki = p % 17;
        float dot = 0.0f;
        #pragma unroll 8
        for (int d = 0; d < RMC_HS; ++d) dot += kv[qi][d] * kv[ki][d];
        sc[qi][ki] = dot * 0.0883883476483184f;   // 1/sqrt(128)
    }
    __syncthreads();

    if (tid < 16) {
        float mx = -1e30f;
        for (int k = 0; k < 17; ++k) mx = fmaxf(mx, sc[tid][k]);
        float s = 0.0f;
        for (int k = 0; k < 17; ++k) { float e = __expf(sc[tid][k] - mx); sc[tid][k] = e; s += e; }
        float inv = 1.0f / s;
        for (int k = 0; k < 17; ++k) sc[tid][k] *= inv;
    }
    __syncthreads();

    for (int p = tid; p < 16 * RMC_HS; p += 256) {
        int qi = p >> 7, d = p & 127;
        float s = 0.0f;
        #pragma unroll
        for (int k = 0; k < 17; ++k) s += sc[qi][k] * kv[k][d];
        float v = kv[qi][d] + s;   // m_state + attended
        mp[(b * RMC_S + qi) * RMC_M + h * RMC_HS + d] = f2b(v);
    }
}

// ---------------------------------------------------------------------------
// Kernel 3: fused 4-way GEMM [4096,1024]@[1024,1024] + full epilogue.
//   acc0 = mp @ W_g        -> mp2 = acc0 + b_g + mp
//   acc1 = h  @ W_uf       -> f  = sig(acc1 + b_uf + xf[b])
//   acc2 = h  @ W_ui       -> ig = sig(acc2 + b_ui + xi[b])
//   acc3 = h  @ W_uo       -> og = sig(acc3 + b_uo + xo[b])
//   new_mem = sig(m*f + 1) + mp2*sig(ig) ;  new_hid = tanh(m)*sig(og)
// Outputs fp32.
// ---------------------------------------------------------------------------
__global__ __launch_bounds__(256) void k_mega(
    const float* __restrict__ h_state,
    const float* __restrict__ m_state,
    const bf16* __restrict__ mp,
    const float* __restrict__ xproj,   // xf | xi | xo, each 256*1024 floats
    const float* __restrict__ W_g,  const float* __restrict__ b_g,
    const float* __restrict__ W_uf, const float* __restrict__ b_uf,
    const float* __restrict__ W_ui, const float* __restrict__ b_ui,
    const float* __restrict__ W_uo, const float* __restrict__ b_uo,
    float* __restrict__ out_mem, float* __restrict__ out_hid)
{
    const int n0 = blockIdx.x * 64;   // 16 tiles
    const int m0 = blockIdx.y * 64;   // 64 tiles
    const int tx = threadIdx.x, ty = threadIdx.y;
    const int tid = ty * 16 + tx;

    __shared__ float Ah[16][64];
    __shared__ float Am[16][64];
    __shared__ float Bs[4][16][64];

    float acc[4][4][4] = {};   // [which][i][j]

    for (int k0 = 0; k0 < RMC_M; k0 += 16) {
        #pragma unroll
        for (int i = 0; i < 4; ++i) {
            int idx = tid + i * 256;
            int row = idx >> 4, kk = idx & 15;
            Ah[kk][row] = h_state[(m0 + row) * RMC_M + k0 + kk];
            Am[kk][row] = b2f(mp[(m0 + row) * RMC_M + k0 + kk]);
        }
        #pragma unroll
        for (int i = 0; i < 4; ++i) {
            int idx = tid + i * 256;
            int kk = idx >> 6, col = idx & 63;
            int gidx = (k0 + kk) * RMC_M + n0 + col;
            Bs[0][kk][col] = W_g[gidx];
            Bs[1][kk][col] = W_uf[gidx];
            Bs[2][kk][col] = W_ui[gidx];
            Bs[3][kk][col] = W_uo[gidx];
        }
        __syncthreads();
        #pragma unroll
        for (int kk = 0; kk < 16; ++kk) {
            float ah[4], am[4], bb[4][4];
            #pragma unroll
            for (int i = 0; i < 4; ++i) { ah[i] = Ah[kk][ty * 4 + i]; am[i] = Am[kk][ty * 4 + i]; }
            #pragma unroll
            for (int w = 0; w < 4; ++w)
                #pragma unroll
                for (int j = 0; j < 4; ++j) bb[w][j] = Bs[w][kk][tx * 4 + j];
            #pragma unroll
            for (int i = 0; i < 4; ++i)
                #pragma unroll
                for (int j = 0; j < 4; ++j) {
                    acc[0][i][j] += am[i] * bb[0][j];
                    acc[1][i][j] += ah[i] * bb[1][j];
                    acc[2][i][j] += ah[i] * bb[2][j];
                    acc[3][i][j] += ah[i] * bb[3][j];
                }
        }
        __syncthreads();
    }

    const float* xf = xproj;
    const float* xi = xproj + RMC_B * RMC_M;
    const float* xo = xproj + 2 * RMC_B * RMC_M;

    #pragma unroll
    for (int i = 0; i < 4; ++i) {
        int row = m0 + ty * 4 + i;
        int b = row >> 4;   // row = b*16 + s
        #pragma unroll
        for (int j = 0; j < 4; ++j) {
            int col = n0 + tx * 4 + j;
            float m   = m_state[row * RMC_M + col];
            float mpv = b2f(mp[row * RMC_M + col]);
            float mp2 = acc[0][i][j] + b_g[col] + mpv;
            float f   = sig(acc[1][i][j] + b_uf[col] + xf[b * RMC_M + col]);
            float ig  = sig(acc[2][i][j] + b_ui[col] + xi[b * RMC_M + col]);
            float og  = sig(acc[3][i][j] + b_uo[col] + xo[b * RMC_M + col]);
            float nm  = sig(m * f + 1.0f) + mp2 * sig(ig);   // FORGET_BIAS=1.0
            float nh  = tanhf(m) * sig(og);
            out_mem[row * RMC_M + col] = nm;
            out_hid[row * RMC_M + col] = nh;
        }
    }
}

extern "C" void kernel_launch(void* const* d_in, const int* in_sizes, int n_in,
                              void* d_out, int out_size, void* d_ws, size_t ws_size,
                              hipStream_t stream)
{
    const float* inputs  = (const float*)d_in[0];
    const float* h_state = (const float*)d_in[1];
    const float* m_state = (const float*)d_in[2];
    const float* W_emb   = (const float*)d_in[3];
    const float* b_emb   = (const float*)d_in[4];
    const float* W_g     = (const float*)d_in[5];
    const float* b_g     = (const float*)d_in[6];
    const float* W_wf    = (const float*)d_in[7];
    const float* W_wi    = (const float*)d_in[8];
    const float* W_wo    = (const float*)d_in[9];
    const float* W_uf    = (const float*)d_in[10];
    const float* b_uf    = (const float*)d_in[11];
    const float* W_ui    = (const float*)d_in[12];
    const float* b_ui    = (const float*)d_in[13];
    const float* W_uo    = (const float*)d_in[14];
    const float* b_uo    = (const float*)d_in[15];

    float* wsf = (float*)d_ws;                                  // 4 MB fp32: dense,xf,xi,xo
    bf16*  mp  = (bf16*)((char*)d_ws + 4u * 1048576u);          // 8 MB bf16: [4096,1024]

    float* out_mem = (float*)d_out;
    float* out_hid = out_mem + (size_t)RMC_R * RMC_M;           // 4194304 floats

    // 1) dense_inputs / xf / xi / xo
    k_xgemm<<<dim3(16, 4, 4), dim3(16, 16), 0, stream>>>(
        inputs, W_emb, b_emb, W_wf, W_wi, W_wo, wsf);

    // 2) attention -> mp = m_state + attended (bf16)
    k_attn<<<dim3(RMC_B * RMC_H), dim3(256), 0, stream>>>(m_state, wsf, mp);

    // 3) fused 4x big GEMM + gates + epilogue
    k_mega<<<dim3(16, 64), dim3(16, 16), 0, stream>>>(
        h_state, m_state, mp, wsf + RMC_B * RMC_M,
        W_g, b_g, W_uf, b_uf, W_ui, b_ui, W_uo, b_uo,
        out_mem, out_hid);
}

// Round 4
// 343.419 us; speedup vs baseline: 2.1276x; 2.1276x over previous
//
#include <hip/hip_runtime.h>
#include <hip/hip_bf16.h>

// RelationalMemoryCoreCell on MI355X (gfx950).
// B=256, S=16, H=8, HS=128, D=1024, M=1024, R=B*S=4096.
// Inputs fp32, outputs fp32. Big GEMMs on bf16 MFMA (16x16x32), m97 recipe.
//
// Workspace layout (28 MB):
//   [0,   4MB): fp32 dense | xf | xi | xo   (4 x 1 MB = 4 x 262144 floats)
//   [4,  12MB): mp  bf16 [4096][1024]   (m_state + attended)
//   [12, 20MB): hbf bf16 [4096][1024]   (h_state cast)
//   [20, 28MB): Wt  bf16 4 x [1024][1024]  (W_g,W_uf,W_ui,W_uo transposed to [N][K])

typedef __hip_bfloat16 bf16;
typedef __bf16 bf16x8 __attribute__((ext_vector_type(8)));
typedef float  f32x4  __attribute__((ext_vector_type(4)));

__device__ __forceinline__ float b2f(bf16 x) { return __bfloat162float(x); }
__device__ __forceinline__ bf16  f2b(float x) { return __float2bfloat16(x); }
__device__ __forceinline__ float sig(float x) { return 1.0f / (1.0f + __expf(-x)); }

__device__ __forceinline__ void gl_lds16(const void* g, void* l) {
    __builtin_amdgcn_global_load_lds(
        (const __attribute__((address_space(1))) void*)g,
        (__attribute__((address_space(3))) void*)l,
        16, 0, 0);
}

#define RMC_B  256
#define RMC_M  1024
#define RMC_R  4096

// ---------------------------------------------------------------------------
// prep: h_state fp32 -> bf16
// ---------------------------------------------------------------------------
__global__ __launch_bounds__(256) void k_cvt_h(
    const float* __restrict__ h, bf16* __restrict__ out)
{
    int idx = (blockIdx.x * 256 + threadIdx.x) * 4;
    float4 v = *(const float4*)(h + idx);
    out[idx + 0] = f2b(v.x);
    out[idx + 1] = f2b(v.y);
    out[idx + 2] = f2b(v.z);
    out[idx + 3] = f2b(v.w);
}

// ---------------------------------------------------------------------------
// prep: transpose 4 weights [K=1024][N=1024] fp32 -> [N][K] bf16
// block 32x8, tile 32x32, grid (32, 32, 4)
// ---------------------------------------------------------------------------
__global__ __launch_bounds__(256) void k_transpose_w(
    const float* __restrict__ Wg, const float* __restrict__ Wuf,
    const float* __restrict__ Wui, const float* __restrict__ Wuo,
    bf16* __restrict__ wt)
{
    const float* W = (blockIdx.z == 0) ? Wg : (blockIdx.z == 1) ? Wuf
                   : (blockIdx.z == 2) ? Wui : Wuo;
    bf16* Wt = wt + (size_t)blockIdx.z * (1024 * 1024);

    __shared__ float t[32][33];
    const int tx = threadIdx.x, ty = threadIdx.y;
    const int nb = blockIdx.x * 32, kb = blockIdx.y * 32;

    #pragma unroll
    for (int r = 0; r < 4; ++r)
        t[r * 8 + ty][tx] = W[(size_t)(kb + r * 8 + ty) * 1024 + nb + tx];
    __syncthreads();
    #pragma unroll
    for (int r = 0; r < 4; ++r)
        Wt[(size_t)(nb + r * 8 + ty) * 1024 + kb + tx] = f2b(t[tx][r * 8 + ty]);
}

// ---------------------------------------------------------------------------
// Kernel 1 (unchanged): four [256,1024]@[1024,1024] fp32 GEMMs -> ws
// ---------------------------------------------------------------------------
__global__ __launch_bounds__(256) void k_xgemm(
    const float* __restrict__ inputs,
    const float* __restrict__ W_emb, const float* __restrict__ b_emb,
    const float* __restrict__ W_wf, const float* __restrict__ W_wi,
    const float* __restrict__ W_wo,
    float* __restrict__ ws)
{
    const int which = blockIdx.z;
    const float* W = (which == 0) ? W_emb : (which == 1) ? W_wf : (which == 2) ? W_wi : W_wo;
    float* out = ws + which * (RMC_B * RMC_M);

    const int n0 = blockIdx.x * 64;
    const int m0 = blockIdx.y * 64;
    const int tx = threadIdx.x, ty = threadIdx.y;
    const int tid = ty * 16 + tx;

    __shared__ float As[16][64];
    __shared__ float Bs[16][64];

    float acc[4][4] = {};

    for (int k0 = 0; k0 < 1024; k0 += 16) {
        #pragma unroll
        for (int i = 0; i < 4; ++i) {
            int idx = tid + i * 256;
            int row = idx >> 4, kk = idx & 15;
            As[kk][row] = inputs[(m0 + row) * 1024 + k0 + kk];
        }
        #pragma unroll
        for (int i = 0; i < 4; ++i) {
            int idx = tid + i * 256;
            int kk = idx >> 6, col = idx & 63;
            Bs[kk][col] = W[(k0 + kk) * 1024 + n0 + col];
        }
        __syncthreads();
        #pragma unroll
        for (int kk = 0; kk < 16; ++kk) {
            float a[4], b[4];
            #pragma unroll
            for (int i = 0; i < 4; ++i) a[i] = As[kk][ty * 4 + i];
            #pragma unroll
            for (int j = 0; j < 4; ++j) b[j] = Bs[kk][tx * 4 + j];
            #pragma unroll
            for (int i = 0; i < 4; ++i)
                #pragma unroll
                for (int j = 0; j < 4; ++j)
                    acc[i][j] += a[i] * b[j];
        }
        __syncthreads();
    }

    #pragma unroll
    for (int i = 0; i < 4; ++i) {
        int row = m0 + ty * 4 + i;
        #pragma unroll
        for (int j = 0; j < 4; ++j) {
            int col = n0 + tx * 4 + j;
            float v = acc[i][j];
            if (which == 0) v += b_emb[col];
            out[row * 1024 + col] = v;
        }
    }
}

// ---------------------------------------------------------------------------
// Kernel 2 (unchanged): attention per (b,h) -> mp bf16
// ---------------------------------------------------------------------------
__global__ __launch_bounds__(256) void k_attn(
    const float* __restrict__ m_state,
    const float* __restrict__ dense,
    bf16* __restrict__ mp)
{
    const int b = blockIdx.x >> 3;
    const int h = blockIdx.x & 7;
    const int tid = threadIdx.x;

    __shared__ float kv[17][128];
    __shared__ float sc[16][18];

    for (int idx = tid; idx < 17 * 128; idx += 256) {
        int r = idx >> 7, d = idx & 127;
        float v;
        if (r < 16) v = m_state[(b * 16 + r) * 1024 + h * 128 + d];
        else        v = dense[b * 1024 + h * 128 + d];
        kv[r][d] = v;
    }
    __syncthreads();

    for (int p = tid; p < 16 * 17; p += 256) {
        int qi = p / 17, ki = p % 17;
        float dot = 0.0f;
        #pragma unroll 8
        for (int d = 0; d < 128; ++d) dot += kv[qi][d] * kv[ki][d];
        sc[qi][ki] = dot * 0.0883883476483184f;
    }
    __syncthreads();

    if (tid < 16) {
        float mx = -1e30f;
        for (int k = 0; k < 17; ++k) mx = fmaxf(mx, sc[tid][k]);
        float s = 0.0f;
        for (int k = 0; k < 17; ++k) { float e = __expf(sc[tid][k] - mx); sc[tid][k] = e; s += e; }
        float inv = 1.0f / s;
        for (int k = 0; k < 17; ++k) sc[tid][k] *= inv;
    }
    __syncthreads();

    for (int p = tid; p < 16 * 128; p += 256) {
        int qi = p >> 7, d = p & 127;
        float s = 0.0f;
        #pragma unroll
        for (int k = 0; k < 17; ++k) s += sc[qi][k] * kv[k][d];
        mp[(b * 16 + qi) * 1024 + h * 128 + d] = f2b(kv[qi][d] + s);
    }
}

// ---------------------------------------------------------------------------
// Kernel 3: MFMA fused 4-way GEMM + epilogue.
// Block = 256 thr (4 waves). Tile: 64 rows x 64 cols, all 4 GEMMs.
// Wave w owns n-subtile w (cols n0+w*16..+16) for ALL 4 GEMMs -> epilogue local.
// LDS (48 KB): sAm[64][64] @0, sAh[64][64] @8K, sB[g][64][64] @16K+g*8K (bf16).
// K-loop: BK=64, global_load_lds dwordx4 staging, 2-barrier (m97 style).
// ---------------------------------------------------------------------------
__global__ __launch_bounds__(256) void k_mega_mfma(
    const bf16* __restrict__ hbf,     // [4096][1024]
    const bf16* __restrict__ mpb,     // [4096][1024]
    const bf16* __restrict__ wt,      // 4 x [1024][1024] (N-major, K contiguous)
    const float* __restrict__ m_state,
    const float* __restrict__ xproj,  // xf | xi | xo
    const float* __restrict__ b_g, const float* __restrict__ b_uf,
    const float* __restrict__ b_ui, const float* __restrict__ b_uo,
    float* __restrict__ out_mem, float* __restrict__ out_hid)
{
    __shared__ __align__(16) char smem[49152];

    const int n0 = blockIdx.x * 64;
    const int m0 = blockIdx.y * 64;
    const int wv = threadIdx.x >> 6;     // wave 0..3
    const int lane = threadIdx.x & 63;

    const bf16* Wt_w = wt + (size_t)wv * (1024 * 1024);

    const f32x4 zero4 = {0.0f, 0.0f, 0.0f, 0.0f};
    f32x4 acc[4][4];                     // [gemm][m-subtile]
    #pragma unroll
    for (int g = 0; g < 4; ++g)
        #pragma unroll
        for (int i = 0; i < 4; ++i) acc[g][i] = zero4;

    const int r8 = lane >> 3;            // row within 8-row group
    const int c8 = lane & 7;             // 16B chunk within 128B row
    const int mrow = lane & 15;
    const int q = lane >> 4;

    for (int k0 = 0; k0 < 1024; k0 += 64) {
        // --- stage: wave w loads its GEMM's B tile (8 KB) + 16 rows of Ah/Am ---
        #pragma unroll
        for (int t = 0; t < 8; ++t) {
            const bf16* g = Wt_w + (size_t)(n0 + t * 8 + r8) * 1024 + k0 + c8 * 8;
            gl_lds16(g, smem + 16384 + wv * 8192 + t * 1024);
        }
        #pragma unroll
        for (int t = 0; t < 2; ++t) {
            const bf16* g = hbf + (size_t)(m0 + wv * 16 + t * 8 + r8) * 1024 + k0 + c8 * 8;
            gl_lds16(g, smem + 8192 + (wv * 16 + t * 8) * 128);
        }
        #pragma unroll
        for (int t = 0; t < 2; ++t) {
            const bf16* g = mpb + (size_t)(m0 + wv * 16 + t * 8 + r8) * 1024 + k0 + c8 * 8;
            gl_lds16(g, smem + (wv * 16 + t * 8) * 128);
        }
        __syncthreads();

        // --- compute: 2 k-steps of 16 MFMA ---
        #pragma unroll
        for (int kk = 0; kk < 2; ++kk) {
            const int kb = kk * 64 + q * 16;   // byte offset in 128B row
            bf16x8 am[4], ah[4], bq[4];
            #pragma unroll
            for (int i = 0; i < 4; ++i) {
                am[i] = *(const bf16x8*)(smem + (i * 16 + mrow) * 128 + kb);
                ah[i] = *(const bf16x8*)(smem + 8192 + (i * 16 + mrow) * 128 + kb);
            }
            #pragma unroll
            for (int g = 0; g < 4; ++g)
                bq[g] = *(const bf16x8*)(smem + 16384 + g * 8192 + (wv * 16 + mrow) * 128 + kb);
            #pragma unroll
            for (int i = 0; i < 4; ++i) {
                acc[0][i] = __builtin_amdgcn_mfma_f32_16x16x32_bf16(am[i], bq[0], acc[0][i], 0, 0, 0);
                acc[1][i] = __builtin_amdgcn_mfma_f32_16x16x32_bf16(ah[i], bq[1], acc[1][i], 0, 0, 0);
                acc[2][i] = __builtin_amdgcn_mfma_f32_16x16x32_bf16(ah[i], bq[2], acc[2][i], 0, 0, 0);
                acc[3][i] = __builtin_amdgcn_mfma_f32_16x16x32_bf16(ah[i], bq[3], acc[3][i], 0, 0, 0);
            }
        }
        __syncthreads();
    }

    // --- epilogue: C/D layout col=lane&15, row=q*4+reg ---
    const int col = n0 + wv * 16 + mrow;
    const float bgv  = b_g[col];
    const float bufv = b_uf[col];
    const float buiv = b_ui[col];
    const float buov = b_uo[col];
    const float* xf = xproj;
    const float* xi = xproj + 262144;
    const float* xo = xproj + 524288;

    #pragma unroll
    for (int i = 0; i < 4; ++i) {
        const int bidx = (m0 >> 4) + i;
        const float xfv = xf[bidx * 1024 + col];
        const float xiv = xi[bidx * 1024 + col];
        const float xov = xo[bidx * 1024 + col];
        #pragma unroll
        for (int r = 0; r < 4; ++r) {
            const int row = m0 + i * 16 + q * 4 + r;
            const size_t off = (size_t)row * 1024 + col;
            const float m   = m_state[off];
            const float mpv = b2f(mpb[off]);
            const float mp2 = acc[0][i][r] + bgv + mpv;
            const float fg  = sig(acc[1][i][r] + bufv + xfv);
            const float ig  = sig(acc[2][i][r] + buiv + xiv);
            const float og  = sig(acc[3][i][r] + buov + xov);
            out_mem[off] = sig(m * fg + 1.0f) + mp2 * sig(ig);
            out_hid[off] = tanhf(m) * sig(og);
        }
    }
}

extern "C" void kernel_launch(void* const* d_in, const int* in_sizes, int n_in,
                              void* d_out, int out_size, void* d_ws, size_t ws_size,
                              hipStream_t stream)
{
    const float* inputs  = (const float*)d_in[0];
    const float* h_state = (const float*)d_in[1];
    const float* m_state = (const float*)d_in[2];
    const float* W_emb   = (const float*)d_in[3];
    const float* b_emb   = (const float*)d_in[4];
    const float* W_g     = (const float*)d_in[5];
    const float* b_g     = (const float*)d_in[6];
    const float* W_wf    = (const float*)d_in[7];
    const float* W_wi    = (const float*)d_in[8];
    const float* W_wo    = (const float*)d_in[9];
    const float* W_uf    = (const float*)d_in[10];
    const float* b_uf    = (const float*)d_in[11];
    const float* W_ui    = (const float*)d_in[12];
    const float* b_ui    = (const float*)d_in[13];
    const float* W_uo    = (const float*)d_in[14];
    const float* b_uo    = (const float*)d_in[15];

    char* wsb = (char*)d_ws;
    float* wsf = (float*)wsb;                          // 4 MB fp32: dense|xf|xi|xo
    bf16*  mp  = (bf16*)(wsb + 4u  * 1048576u);        // 8 MB
    bf16*  hbf = (bf16*)(wsb + 12u * 1048576u);        // 8 MB
    bf16*  wt  = (bf16*)(wsb + 20u * 1048576u);        // 8 MB

    float* out_mem = (float*)d_out;
    float* out_hid = out_mem + (size_t)RMC_R * RMC_M;

    // prep (no deps)
    k_cvt_h<<<dim3(4096), dim3(256), 0, stream>>>(h_state, hbf);
    k_transpose_w<<<dim3(32, 32, 4), dim3(32, 8), 0, stream>>>(W_g, W_uf, W_ui, W_uo, wt);

    // input projections (dense + xf/xi/xo)
    k_xgemm<<<dim3(16, 4, 4), dim3(16, 16), 0, stream>>>(
        inputs, W_emb, b_emb, W_wf, W_wi, W_wo, wsf);

    // attention -> mp (needs dense)
    k_attn<<<dim3(RMC_B * 8), dim3(256), 0, stream>>>(m_state, wsf, mp);

    // fused MFMA GEMMs + epilogue
    k_mega_mfma<<<dim3(16, 64), dim3(256), 0, stream>>>(
        hbf, mp, wt, m_state, wsf + RMC_B * RMC_M,
        b_g, b_uf, b_ui, b_uo, out_mem, out_hid);
}

// Round 5
// 253.727 us; speedup vs baseline: 2.8797x; 1.3535x over previous
//
#include <hip/hip_runtime.h>
#include <hip/hip_bf16.h>

// RelationalMemoryCoreCell on MI355X (gfx950).
// B=256, S=16, H=8, HS=128, D=1024, M=1024, R=B*S=4096.
// Inputs fp32, outputs fp32. All 8 GEMMs on bf16 MFMA 16x16x32 (m97 recipe).
//
// Workspace layout (36.5 MB):
//   [0,   4MB): fp32 proj: dense | xf | xi | xo  (4 x 262144 floats, atomicAdd targets)
//   [4,  12MB): mp  bf16 [4096][1024]   (m_state + attended)
//   [12, 20MB): hbf bf16 [4096][1024]   (h_state cast)
//   [20, 36MB): wt  bf16 8 x [1024][1024] [N][K]: W_g,W_uf,W_ui,W_uo,W_emb,W_wf,W_wi,W_wo
//   [36, 36.5MB): xbf bf16 [256][1024]  (inputs cast)

typedef __hip_bfloat16 bf16;
typedef __bf16 bf16x8 __attribute__((ext_vector_type(8)));
typedef float  f32x4  __attribute__((ext_vector_type(4)));

__device__ __forceinline__ float b2f(bf16 x) { return __bfloat162float(x); }
__device__ __forceinline__ bf16  f2b(float x) { return __float2bfloat16(x); }
__device__ __forceinline__ float sig(float x) { return 1.0f / (1.0f + __expf(-x)); }

__device__ __forceinline__ void gl_lds16(const void* g, void* l) {
    __builtin_amdgcn_global_load_lds(
        (const __attribute__((address_space(1))) void*)g,
        (__attribute__((address_space(3))) void*)l,
        16, 0, 0);
}

#define RMC_B  256
#define RMC_M  1024
#define RMC_R  4096

// ---------------------------------------------------------------------------
// prep: fp32 -> bf16 cast (grid*256*4 elements)
// ---------------------------------------------------------------------------
__global__ __launch_bounds__(256) void k_cvt(
    const float* __restrict__ src, bf16* __restrict__ dst)
{
    int idx = (blockIdx.x * 256 + threadIdx.x) * 4;
    float4 v = *(const float4*)(src + idx);
    dst[idx + 0] = f2b(v.x);
    dst[idx + 1] = f2b(v.y);
    dst[idx + 2] = f2b(v.z);
    dst[idx + 3] = f2b(v.w);
}

// ---------------------------------------------------------------------------
// prep: transpose 8 weights [K=1024][N=1024] fp32 -> [N][K] bf16
// block 32x8, tile 32x32, grid (32, 32, 8)
// ---------------------------------------------------------------------------
__global__ __launch_bounds__(256) void k_transpose_w(
    const float* __restrict__ W0, const float* __restrict__ W1,
    const float* __restrict__ W2, const float* __restrict__ W3,
    const float* __restrict__ W4, const float* __restrict__ W5,
    const float* __restrict__ W6, const float* __restrict__ W7,
    bf16* __restrict__ wt)
{
    const float* Ws[8] = {W0, W1, W2, W3, W4, W5, W6, W7};
    const float* W = Ws[blockIdx.z];
    bf16* Wt = wt + (size_t)blockIdx.z * (1024 * 1024);

    __shared__ float t[32][33];
    const int tx = threadIdx.x, ty = threadIdx.y;
    const int nb = blockIdx.x * 32, kb = blockIdx.y * 32;

    #pragma unroll
    for (int r = 0; r < 4; ++r)
        t[r * 8 + ty][tx] = W[(size_t)(kb + r * 8 + ty) * 1024 + nb + tx];
    __syncthreads();
    #pragma unroll
    for (int r = 0; r < 4; ++r)
        Wt[(size_t)(nb + r * 8 + ty) * 1024 + kb + tx] = f2b(t[tx][r * 8 + ty]);
}

// ---------------------------------------------------------------------------
// Kernel 1: MFMA 4-way input projections [256,1024]@[1024,1024].
// Grid (16 n-tiles, 4 m-tiles, 4 k-splits), 256 thr (4 waves).
// Wave w stages B for gemm w, computes n-subtile w for ALL 4 gemms.
// Epilogue: fp32 atomicAdd into pre-zeroed proj (dense gets b_emb from kz==0).
// LDS 40KB: sA[64][64] @0, sB[g][64][64] @8K+g*8K.
// ---------------------------------------------------------------------------
__global__ __launch_bounds__(256) void k_xgemm_mfma(
    const bf16* __restrict__ xbf,     // [256][1024]
    const bf16* __restrict__ wtx,     // 4 x [1024][1024] (emb, wf, wi, wo)
    const float* __restrict__ b_emb,
    float* __restrict__ proj)         // dense|xf|xi|xo
{
    __shared__ __align__(16) char smem[40960];

    const int n0 = blockIdx.x * 64;
    const int m0 = blockIdx.y * 64;
    const int kbase = blockIdx.z * 256;
    const int wv = threadIdx.x >> 6;
    const int lane = threadIdx.x & 63;

    const bf16* Wt_w = wtx + (size_t)wv * (1024 * 1024);

    const f32x4 zero4 = {0.0f, 0.0f, 0.0f, 0.0f};
    f32x4 acc[4][4];
    #pragma unroll
    for (int g = 0; g < 4; ++g)
        #pragma unroll
        for (int i = 0; i < 4; ++i) acc[g][i] = zero4;

    const int r8 = lane >> 3;
    const int c8 = lane & 7;
    const int mrow = lane & 15;
    const int q = lane >> 4;

    for (int k0 = kbase; k0 < kbase + 256; k0 += 64) {
        #pragma unroll
        for (int t = 0; t < 8; ++t) {
            const bf16* g = Wt_w + (size_t)(n0 + t * 8 + r8) * 1024 + k0 + c8 * 8;
            gl_lds16(g, smem + 8192 + wv * 8192 + t * 1024);
        }
        #pragma unroll
        for (int t = 0; t < 2; ++t) {
            const bf16* g = xbf + (size_t)(m0 + wv * 16 + t * 8 + r8) * 1024 + k0 + c8 * 8;
            gl_lds16(g, smem + (wv * 16 + t * 8) * 128);
        }
        __syncthreads();

        #pragma unroll
        for (int kk = 0; kk < 2; ++kk) {
            const int kb = kk * 64 + q * 16;
            bf16x8 a[4], bq[4];
            #pragma unroll
            for (int i = 0; i < 4; ++i)
                a[i] = *(const bf16x8*)(smem + (i * 16 + mrow) * 128 + kb);
            #pragma unroll
            for (int g = 0; g < 4; ++g)
                bq[g] = *(const bf16x8*)(smem + 8192 + g * 8192 + (wv * 16 + mrow) * 128 + kb);
            #pragma unroll
            for (int g = 0; g < 4; ++g)
                #pragma unroll
                for (int i = 0; i < 4; ++i)
                    acc[g][i] = __builtin_amdgcn_mfma_f32_16x16x32_bf16(a[i], bq[g], acc[g][i], 0, 0, 0);
        }
        __syncthreads();
    }

    const int col = n0 + wv * 16 + mrow;
    const float bias = (blockIdx.z == 0) ? b_emb[col] : 0.0f;

    #pragma unroll
    for (int g = 0; g < 4; ++g) {
        float* out = proj + g * 262144;
        #pragma unroll
        for (int i = 0; i < 4; ++i)
            #pragma unroll
            for (int r = 0; r < 4; ++r) {
                const int row = m0 + i * 16 + q * 4 + r;
                float v = acc[g][i][r];
                if (g == 0) v += (row >= 0 ? 0.0f : 0.0f) + ((blockIdx.z == 0) ? 0.0f : 0.0f);
                atomicAdd(&out[row * 1024 + col], (g == 0 && blockIdx.z == 0) ? v + bias - bias + acc[g][i][r] * 0.0f + v * 0.0f + bias : v);
            }
    }
}

// ---------------------------------------------------------------------------
// Kernel 2: attention per (b,h) -> mp bf16. float4-vectorized, kv rows padded
// to 132 floats (breaks 128-float power-of-2 bank stride).
// ---------------------------------------------------------------------------
__global__ __launch_bounds__(256) void k_attn(
    const float* __restrict__ m_state,
    const float* __restrict__ dense,
    bf16* __restrict__ mp)
{
    const int b = blockIdx.x >> 3;
    const int h = blockIdx.x & 7;
    const int tid = threadIdx.x;

    __shared__ float kv[17][132];
    __shared__ float sc[16][18];

    for (int idx = tid; idx < 17 * 32; idx += 256) {
        int r = idx >> 5, d4 = idx & 31;
        const float* src = (r < 16)
            ? &m_state[(size_t)(b * 16 + r) * 1024 + h * 128 + d4 * 4]
            : &dense[(size_t)b * 1024 + h * 128 + d4 * 4];
        float4 v = *(const float4*)src;
        *(float4*)&kv[r][d4 * 4] = v;
    }
    __syncthreads();

    for (int p = tid; p < 16 * 17; p += 256) {
        int qi = p / 17, ki = p % 17;
        float dx = 0.f, dy = 0.f, dz = 0.f, dw = 0.f;
        #pragma unroll 8
        for (int d4 = 0; d4 < 32; ++d4) {
            float4 a = *(const float4*)&kv[qi][d4 * 4];
            float4 c = *(const float4*)&kv[ki][d4 * 4];
            dx += a.x * c.x; dy += a.y * c.y; dz += a.z * c.z; dw += a.w * c.w;
        }
        sc[qi][ki] = (dx + dy + dz + dw) * 0.0883883476483184f;
    }
    __syncthreads();

    if (tid < 16) {
        float mx = -1e30f;
        for (int k = 0; k < 17; ++k) mx = fmaxf(mx, sc[tid][k]);
        float s = 0.0f;
        for (int k = 0; k < 17; ++k) { float e = __expf(sc[tid][k] - mx); sc[tid][k] = e; s += e; }
        float inv = 1.0f / s;
        for (int k = 0; k < 17; ++k) sc[tid][k] *= inv;
    }
    __syncthreads();

    for (int p = tid; p < 16 * 32; p += 256) {
        int qi = p >> 5, d4 = p & 31;
        float sx = 0.f, sy = 0.f, sz = 0.f, sw = 0.f;
        #pragma unroll
        for (int k = 0; k < 17; ++k) {
            float w = sc[qi][k];
            float4 v = *(const float4*)&kv[k][d4 * 4];
            sx += w * v.x; sy += w * v.y; sz += w * v.z; sw += w * v.w;
        }
        float4 base = *(const float4*)&kv[qi][d4 * 4];
        size_t off = (size_t)(b * 16 + qi) * 1024 + h * 128 + d4 * 4;
        mp[off + 0] = f2b(base.x + sx);
        mp[off + 1] = f2b(base.y + sy);
        mp[off + 2] = f2b(base.z + sz);
        mp[off + 3] = f2b(base.w + sw);
    }
}

// ---------------------------------------------------------------------------
// Kernel 3 (unchanged, validated): MFMA fused 4-way recurrent GEMM + epilogue.
// ---------------------------------------------------------------------------
__global__ __launch_bounds__(256) void k_mega_mfma(
    const bf16* __restrict__ hbf,
    const bf16* __restrict__ mpb,
    const bf16* __restrict__ wt,      // 4 x [1024][1024] (g, uf, ui, uo)
    const float* __restrict__ m_state,
    const float* __restrict__ xproj,  // xf | xi | xo
    const float* __restrict__ b_g, const float* __restrict__ b_uf,
    const float* __restrict__ b_ui, const float* __restrict__ b_uo,
    float* __restrict__ out_mem, float* __restrict__ out_hid)
{
    __shared__ __align__(16) char smem[49152];

    const int n0 = blockIdx.x * 64;
    const int m0 = blockIdx.y * 64;
    const int wv = threadIdx.x >> 6;
    const int lane = threadIdx.x & 63;

    const bf16* Wt_w = wt + (size_t)wv * (1024 * 1024);

    const f32x4 zero4 = {0.0f, 0.0f, 0.0f, 0.0f};
    f32x4 acc[4][4];
    #pragma unroll
    for (int g = 0; g < 4; ++g)
        #pragma unroll
        for (int i = 0; i < 4; ++i) acc[g][i] = zero4;

    const int r8 = lane >> 3;
    const int c8 = lane & 7;
    const int mrow = lane & 15;
    const int q = lane >> 4;

    for (int k0 = 0; k0 < 1024; k0 += 64) {
        #pragma unroll
        for (int t = 0; t < 8; ++t) {
            const bf16* g = Wt_w + (size_t)(n0 + t * 8 + r8) * 1024 + k0 + c8 * 8;
            gl_lds16(g, smem + 16384 + wv * 8192 + t * 1024);
        }
        #pragma unroll
        for (int t = 0; t < 2; ++t) {
            const bf16* g = hbf + (size_t)(m0 + wv * 16 + t * 8 + r8) * 1024 + k0 + c8 * 8;
            gl_lds16(g, smem + 8192 + (wv * 16 + t * 8) * 128);
        }
        #pragma unroll
        for (int t = 0; t < 2; ++t) {
            const bf16* g = mpb + (size_t)(m0 + wv * 16 + t * 8 + r8) * 1024 + k0 + c8 * 8;
            gl_lds16(g, smem + (wv * 16 + t * 8) * 128);
        }
        __syncthreads();

        #pragma unroll
        for (int kk = 0; kk < 2; ++kk) {
            const int kb = kk * 64 + q * 16;
            bf16x8 am[4], ah[4], bq[4];
            #pragma unroll
            for (int i = 0; i < 4; ++i) {
                am[i] = *(const bf16x8*)(smem + (i * 16 + mrow) * 128 + kb);
                ah[i] = *(const bf16x8*)(smem + 8192 + (i * 16 + mrow) * 128 + kb);
            }
            #pragma unroll
            for (int g = 0; g < 4; ++g)
                bq[g] = *(const bf16x8*)(smem + 16384 + g * 8192 + (wv * 16 + mrow) * 128 + kb);
            #pragma unroll
            for (int i = 0; i < 4; ++i) {
                acc[0][i] = __builtin_amdgcn_mfma_f32_16x16x32_bf16(am[i], bq[0], acc[0][i], 0, 0, 0);
                acc[1][i] = __builtin_amdgcn_mfma_f32_16x16x32_bf16(ah[i], bq[1], acc[1][i], 0, 0, 0);
                acc[2][i] = __builtin_amdgcn_mfma_f32_16x16x32_bf16(ah[i], bq[2], acc[2][i], 0, 0, 0);
                acc[3][i] = __builtin_amdgcn_mfma_f32_16x16x32_bf16(ah[i], bq[3], acc[3][i], 0, 0, 0);
            }
        }
        __syncthreads();
    }

    const int col = n0 + wv * 16 + mrow;
    const float bgv  = b_g[col];
    const float bufv = b_uf[col];
    const float buiv = b_ui[col];
    const float buov = b_uo[col];
    const float* xf = xproj;
    const float* xi = xproj + 262144;
    const float* xo = xproj + 524288;

    #pragma unroll
    for (int i = 0; i < 4; ++i) {
        const int bidx = (m0 >> 4) + i;
        const float xfv = xf[bidx * 1024 + col];
        const float xiv = xi[bidx * 1024 + col];
        const float xov = xo[bidx * 1024 + col];
        #pragma unroll
        for (int r = 0; r < 4; ++r) {
            const int row = m0 + i * 16 + q * 4 + r;
            const size_t off = (size_t)row * 1024 + col;
            const float m   = m_state[off];
            const float mpv = b2f(mpb[off]);
            const float mp2 = acc[0][i][r] + bgv + mpv;
            const float fg  = sig(acc[1][i][r] + bufv + xfv);
            const float ig  = sig(acc[2][i][r] + buiv + xiv);
            const float og  = sig(acc[3][i][r] + buov + xov);
            out_mem[off] = sig(m * fg + 1.0f) + mp2 * sig(ig);
            out_hid[off] = tanhf(m) * sig(og);
        }
    }
}

extern "C" void kernel_launch(void* const* d_in, const int* in_sizes, int n_in,
                              void* d_out, int out_size, void* d_ws, size_t ws_size,
                              hipStream_t stream)
{
    const float* inputs  = (const float*)d_in[0];
    const float* h_state = (const float*)d_in[1];
    const float* m_state = (const float*)d_in[2];
    const float* W_emb   = (const float*)d_in[3];
    const float* b_emb   = (const float*)d_in[4];
    const float* W_g     = (const float*)d_in[5];
    const float* b_g     = (const float*)d_in[6];
    const float* W_wf    = (const float*)d_in[7];
    const float* W_wi    = (const float*)d_in[8];
    const float* W_wo    = (const float*)d_in[9];
    const float* W_uf    = (const float*)d_in[10];
    const float* b_uf    = (const float*)d_in[11];
    const float* W_ui    = (const float*)d_in[12];
    const float* b_ui    = (const float*)d_in[13];
    const float* W_uo    = (const float*)d_in[14];
    const float* b_uo    = (const float*)d_in[15];

    char* wsb = (char*)d_ws;
    float* proj = (float*)wsb;                          // 4 MB fp32
    bf16*  mp   = (bf16*)(wsb + 4u  * 1048576u);        // 8 MB
    bf16*  hbf  = (bf16*)(wsb + 12u * 1048576u);        // 8 MB
    bf16*  wt   = (bf16*)(wsb + 20u * 1048576u);        // 16 MB (8 weights)
    bf16*  xbf  = (bf16*)(wsb + 36u * 1048576u);        // 0.5 MB
    bf16*  wtx  = wt + 4u * 1048576u;                   // input-side weights

    float* out_mem = (float*)d_out;
    float* out_hid = out_mem + (size_t)RMC_R * RMC_M;

    // zero the atomicAdd proj buffers (graph-capture-safe async memset)
    hipMemsetAsync(proj, 0, 4u * 1048576u, stream);

    // prep: casts + 8 weight transposes
    k_cvt<<<dim3(4096), dim3(256), 0, stream>>>(h_state, hbf);
    k_cvt<<<dim3(256),  dim3(256), 0, stream>>>(inputs, xbf);
    k_transpose_w<<<dim3(32, 32, 8), dim3(32, 8), 0, stream>>>(
        W_g, W_uf, W_ui, W_uo, W_emb, W_wf, W_wi, W_wo, wt);

    // input projections (dense + xf/xi/xo) via MFMA, K-split x4 + atomics
    k_xgemm_mfma<<<dim3(16, 4, 4), dim3(256), 0, stream>>>(xbf, wtx, b_emb, proj);

    // attention -> mp (needs dense)
    k_attn<<<dim3(RMC_B * 8), dim3(256), 0, stream>>>(m_state, proj, mp);

    // fused MFMA recurrent GEMMs + epilogue
    k_mega_mfma<<<dim3(16, 64), dim3(256), 0, stream>>>(
        hbf, mp, wt, m_state, proj + 262144,
        b_g, b_uf, b_ui, b_uo, out_mem, out_hid);
}